// Round 7
// baseline (414.658 us; speedup 1.0000x reference)
//
#include <hip/hip_runtime.h>
#include <cfloat>
#include <stdint.h>

// Problem geometry (fixed by setup_inputs)
#define D       512
#define NCODES  1024
#define MROWS   32768          // 16 * 2048

// d_out layout (f32 elements): z_st, loss, dist, idx (idx stored as float)
#define ZST_OFF  0
#define LOSS_OFF 16777216
#define DIST_OFF 16777217ull
#define IDX_OFF  50331649

// ws layout:
//   bytes [0, 2 MB)            : split-E image (8 nblk x 256 KB)
//   bytes [2 MB, 2 MB+256 KB)  : u64 packed argmin per row (init 0xFF)
//   floats after               : e2[1024], z2parts[32768][2], loss
#define WS_AMIN_B 2097152
#define WS_E2F    589824                // float index
#define WS_Z2F    590848                // 2 partials per row
#define WS_LOSSF  656384

typedef __attribute__((ext_vector_type(4))) float f32x4;
typedef __attribute__((ext_vector_type(4))) int   i32x4;
typedef __bf16 bf16v8 __attribute__((ext_vector_type(8)));

static __device__ __forceinline__ uint32_t f2bf(float x) {
    // round-to-nearest-even bf16, low 16 bits
    uint32_t u = __float_as_uint(x);
    return (u + 0x7fffu + ((u >> 16) & 1u)) >> 16;
}
static __device__ __forceinline__ float bf2f(uint32_t h) {
    return __uint_as_float(h << 16);
}
static __device__ __forceinline__ f32x4 MFMA(bf16v8 a, bf16v8 b, f32x4 c) {
    return __builtin_amdgcn_mfma_f32_16x16x32_bf16(a, b, c, 0, 0, 0);
}

// ---------------------------------------------------------------------------
// split-E: emb f32 -> bf16 hi/lo image, global_load_lds-ready.
// Image: [nblk 8][kstep 16][col 128][128 B row]; 8 x 16 B slots, content u at
// phys slot u ^ (col&7); u<4 = hi k-octet u, u>=4 = lo k-octet u-4.
// Also zeroes the loss accumulator.
// ---------------------------------------------------------------------------
__global__ void split_e_kernel(const float* __restrict__ emb,
                               char* __restrict__ wsb,
                               float* __restrict__ wsf) {
    if (blockIdx.x == 0 && threadIdx.x == 0) wsf[WS_LOSSF] = 0.0f;
    const int u    = blockIdx.x * 256 + threadIdx.x;   // 0..32767
    const int row  = u >> 5;                           // 0..1023
    const int ks   = (u >> 1) & 15;
    const int half = u & 1;
    const float* p = emb + (size_t)row * D + ks * 32 + half * 16;
    float xs[16];
#pragma unroll
    for (int i = 0; i < 4; ++i) {
        const float4 v = ((const float4*)p)[i];
        xs[4*i] = v.x; xs[4*i+1] = v.y; xs[4*i+2] = v.z; xs[4*i+3] = v.w;
    }
    uint32_t hw[8], lw[8];
#pragma unroll
    for (int i = 0; i < 8; ++i) {
        const float a = xs[2*i], b = xs[2*i+1];
        const uint32_t h0 = f2bf(a), h1 = f2bf(b);
        const uint32_t l0 = f2bf(a - bf2f(h0)), l1 = f2bf(b - bf2f(h1));
        hw[i] = h0 | (h1 << 16);
        lw[i] = l0 | (l1 << 16);
    }
    const int nblk = row >> 7, col = row & 127;
    char* base = wsb + (size_t)nblk * 262144 + (size_t)ks * 16384 + col * 128;
    const int sw = col & 7;
    *(i32x4*)(base + 16 * ((half*2    ) ^ sw)) = i32x4{(int)hw[0],(int)hw[1],(int)hw[2],(int)hw[3]};
    *(i32x4*)(base + 16 * ((half*2 + 1) ^ sw)) = i32x4{(int)hw[4],(int)hw[5],(int)hw[6],(int)hw[7]};
    *(i32x4*)(base + 16 * ((4 + half*2    ) ^ sw)) = i32x4{(int)lw[0],(int)lw[1],(int)lw[2],(int)lw[3]};
    *(i32x4*)(base + 16 * ((4 + half*2 + 1) ^ sw)) = i32x4{(int)lw[4],(int)lw[5],(int)lw[6],(int)lw[7]};
}

// ---------------------------------------------------------------------------
// split-A: residual f32 -> bf16 hi/lo image (same per-tile layout as split-E)
// written into the z_st region of d_out (read-only for gemm; argzst, which is
// stream-ordered after gemm, overwrites it with the real z_st).
// A-image: [mblk 256][kstep 16][row 128][128 B]. Grid 512 = (mblk, ks-half).
// Thread t: row = t>>1, half = t&1; loops 8 k-steps. Deterministic z2 as two
// per-row partials (kh 0/1), summed in gemm.
// ---------------------------------------------------------------------------
__global__ void split_a_kernel(const float* __restrict__ residual,
                               float* __restrict__ wsf,
                               float* __restrict__ out) {
    const int mblk = blockIdx.x >> 1;
    const int kh   = blockIdx.x & 1;
    const int t    = threadIdx.x;
    const int row  = t >> 1, half = t & 1;
    const int row0 = mblk * 128;
    const float* src = residual + (size_t)(row0 + row) * D + half * 16;
    char* img = (char*)out + (size_t)mblk * 262144 + row * 128;
    const int sw = row & 7;
    float s = 0.f;
#pragma unroll
    for (int k8 = 0; k8 < 8; ++k8) {
        const int ks = kh * 8 + k8;
        const float* p = src + ks * 32;
        float xs[16];
#pragma unroll
        for (int i = 0; i < 4; ++i) {
            const float4 v = ((const float4*)p)[i];
            xs[4*i] = v.x; xs[4*i+1] = v.y; xs[4*i+2] = v.z; xs[4*i+3] = v.w;
        }
        uint32_t hw[8], lw[8];
#pragma unroll
        for (int i = 0; i < 8; ++i) {
            const float a = xs[2*i], b = xs[2*i+1];
            s += a * a + b * b;
            const uint32_t h0 = f2bf(a), h1 = f2bf(b);
            const uint32_t l0 = f2bf(a - bf2f(h0)), l1 = f2bf(b - bf2f(h1));
            hw[i] = h0 | (h1 << 16);
            lw[i] = l0 | (l1 << 16);
        }
        char* b = img + (size_t)ks * 16384;
        *(i32x4*)(b + 16 * ((half*2    ) ^ sw)) = i32x4{(int)hw[0],(int)hw[1],(int)hw[2],(int)hw[3]};
        *(i32x4*)(b + 16 * ((half*2 + 1) ^ sw)) = i32x4{(int)hw[4],(int)hw[5],(int)hw[6],(int)hw[7]};
        *(i32x4*)(b + 16 * ((4 + half*2    ) ^ sw)) = i32x4{(int)lw[0],(int)lw[1],(int)lw[2],(int)lw[3]};
        *(i32x4*)(b + 16 * ((4 + half*2 + 1) ^ sw)) = i32x4{(int)lw[4],(int)lw[5],(int)lw[6],(int)lw[7]};
    }
    s += __shfl_xor(s, 1);   // combine the two halves of the row
    if (half == 0) wsf[WS_Z2F + (row0 + row) * 2 + kh] = s;
}

// ---------------------------------------------------------------------------
// e2: deterministic per-row ||e||^2 (argmin depends on e2 -> no atomics).
// ---------------------------------------------------------------------------
__global__ void e2_kernel(const float* __restrict__ emb,
                          float* __restrict__ wsf) {
    const int gw   = (int)((blockIdx.x * blockDim.x + threadIdx.x) >> 6);
    const int lane = threadIdx.x & 63;
    const float4* v = (const float4*)(emb + (size_t)gw * D);
    const float4 a = v[lane * 2];
    const float4 b = v[lane * 2 + 1];
    float s = a.x*a.x + a.y*a.y + a.z*a.z + a.w*a.w
            + b.x*b.x + b.y*b.y + b.z*b.z + b.w*b.w;
#pragma unroll
    for (int off = 32; off > 0; off >>= 1) s += __shfl_xor(s, off);
    if (lane == 0) wsf[WS_E2F + gw] = s;
}

// ---------------------------------------------------------------------------
// GEMM: dist[m,n] = z2[m] + e2[n] - 2<r_m, e_n>, 3-product bf16 hi/lo.
// Grid 2048 = 256 M x 8 N blocks, XCD-bijective swizzle (65 MB fetch, R4/R5).
// 256 threads = 4 waves (2M x 2N), wave tile 64x64, BK=32.
// BOTH operands via global_load_lds double-buffer from pre-swizzled images
// (A: z_st scratch; B: ws). One barrier per K-step; prefetch issued right
// after it -> full MFMA phase to land. LDS 64.5 KB -> 2 blocks/CU.
// Epilogue: dist stores + per-64-col-slab argmin -> packed u64 atomicMin.
// ---------------------------------------------------------------------------
__launch_bounds__(256, 2)
__global__ void gemm_kernel(const char* __restrict__ wsb,
                            const float* __restrict__ wsf,
                            unsigned long long* __restrict__ amin,
                            float* __restrict__ out) {
    __shared__ __align__(16) char smem[66048];   // A0|A1|B0|B1 16K each + z2s
    float* z2s = (float*)(smem + 65536);

    const int t    = threadIdx.x;
    const int lane = t & 63, wid = t >> 6;
    const int ln15 = lane & 15, kg = lane >> 4;
    const int wm   = wid >> 1, wn = wid & 1;

    // XCD-bijective swizzle: 8 n-blocks of an m-group share one XCD's L2
    const int bid  = blockIdx.x;
    const int xcd  = bid & 7, j = bid >> 3;
    const int mblk = xcd * 32 + (j >> 3);
    const int nblk = j & 7;
    const int row0 = mblk * 128;
    const int n0   = nblk * 128;

    if (t < 128)
        z2s[t] = wsf[WS_Z2F + (row0 + t) * 2] + wsf[WS_Z2F + (row0 + t) * 2 + 1];

    // frag LDS byte offsets (within one 16 KB tile)
    int aoffh[4], aoffl[4], boffh[4], boffl[4];
#pragma unroll
    for (int mf = 0; mf < 4; ++mf) {
        const int rA = wm * 64 + mf * 16 + ln15;
        aoffh[mf] = rA * 128 + 16 * ((    kg) ^ (rA & 7));
        aoffl[mf] = rA * 128 + 16 * ((4 + kg) ^ (rA & 7));
    }
#pragma unroll
    for (int nf = 0; nf < 4; ++nf) {
        const int cB = wn * 64 + nf * 16 + ln15;
        boffh[nf] = cB * 128 + 16 * ((    kg) ^ (cB & 7));
        boffl[nf] = cB * 128 + 16 * ((4 + kg) ^ (cB & 7));
    }

    const char* Aimg = (const char*)out + (size_t)mblk * 262144;  // z_st scratch
    const char* Bimg = wsb + (size_t)nblk * 262144;

    auto STAGE = [&](int s) {
        const int b = s & 1;
        const char* ga = Aimg + (size_t)s * 16384 + t * 16;
        char* la = smem + b * 16384 + t * 16;
#pragma unroll
        for (int i = 0; i < 4; ++i)
            __builtin_amdgcn_global_load_lds((const uint32_t*)(ga + i * 4096),
                                             (uint32_t*)(la + i * 4096), 16, 0, 0);
        const char* gb = Bimg + (size_t)s * 16384 + t * 16;
        char* lb = smem + 32768 + b * 16384 + t * 16;
#pragma unroll
        for (int i = 0; i < 4; ++i)
            __builtin_amdgcn_global_load_lds((const uint32_t*)(gb + i * 4096),
                                             (uint32_t*)(lb + i * 4096), 16, 0, 0);
    };

    f32x4 acc[4][4];
#pragma unroll
    for (int mf = 0; mf < 4; ++mf)
#pragma unroll
        for (int nf = 0; nf < 4; ++nf) acc[mf][nf] = 0.f;

    STAGE(0);

    for (int s = 0; s < 16; ++s) {
        __syncthreads();            // drains STAGE(s); buffer (s+1)&1 free
        if (s < 15) STAGE(s + 1);   // lands during this step's MFMA phase

        const char* abuf = smem + (s & 1) * 16384;
        const char* bbuf = smem + 32768 + (s & 1) * 16384;
        bf16v8 ah[4], al[4], bh[4], bl[4];
#pragma unroll
        for (int mf = 0; mf < 4; ++mf) {
            ah[mf] = *(const bf16v8*)(abuf + aoffh[mf]);
            al[mf] = *(const bf16v8*)(abuf + aoffl[mf]);
        }
#pragma unroll
        for (int nf = 0; nf < 4; ++nf) {
            bh[nf] = *(const bf16v8*)(bbuf + boffh[nf]);
            bl[nf] = *(const bf16v8*)(bbuf + boffl[nf]);
        }
#pragma unroll
        for (int mf = 0; mf < 4; ++mf)
#pragma unroll
            for (int nf = 0; nf < 4; ++nf) {
                acc[mf][nf] = MFMA(ah[mf], bh[nf], acc[mf][nf]);
                acc[mf][nf] = MFMA(ah[mf], bl[nf], acc[mf][nf]);
                acc[mf][nf] = MFMA(al[mf], bh[nf], acc[mf][nf]);
            }
    }

    // epilogue: dist stores + per-64-col-slab argmin via packed atomicMin
    float e2v[4];
#pragma unroll
    for (int nf = 0; nf < 4; ++nf)
        e2v[nf] = wsf[WS_E2F + n0 + wn * 64 + nf * 16 + ln15];
#pragma unroll
    for (int mf = 0; mf < 4; ++mf)
#pragma unroll
        for (int j4 = 0; j4 < 4; ++j4) {
            const int rl = wm * 64 + mf * 16 + kg * 4 + j4;
            const float z2 = z2s[rl];
            const size_t rbase = DIST_OFF + (size_t)(row0 + rl) * 1024;
            float bv = FLT_MAX; int bi = 0;
#pragma unroll
            for (int nf = 0; nf < 4; ++nf) {
                const int gcol = n0 + wn * 64 + nf * 16 + ln15;
                const float dv = (z2 + e2v[nf]) - 2.0f * acc[mf][nf][j4];
                out[rbase + gcol] = dv;
                if (dv < bv) { bv = dv; bi = gcol; }   // ascending col scan
            }
#pragma unroll
            for (int off = 1; off < 16; off <<= 1) {
                const float ov = __shfl_xor(bv, off);
                const int   oi = __shfl_xor(bi, off);
                if (ov < bv || (ov == bv && oi < bi)) { bv = ov; bi = oi; }
            }
            if (ln15 == 0) {
                const uint32_t u   = __float_as_uint(bv);
                const uint32_t key = u ^ ((uint32_t)((int)u >> 31) | 0x80000000u);
                const unsigned long long pk =
                    ((unsigned long long)key << 32) | (uint32_t)bi;
                atomicMin(&amin[row0 + rl], pk);
            }
        }
}

// ---------------------------------------------------------------------------
// argzst: decode per-row argmin, then z_st + loss.
// 512 blocks x 256 threads, 64 rows/block; block touches only its own rows.
// ---------------------------------------------------------------------------
__global__ void argzst_kernel(const float* __restrict__ residual,
                              const float* __restrict__ emb,
                              const unsigned long long* __restrict__ amin,
                              float* __restrict__ wsf,
                              float* __restrict__ out) {
    __shared__ int   srow[64];
    __shared__ float swsum[4];
    const int t = threadIdx.x, lane = t & 63, w = t >> 6;
    const int row0 = blockIdx.x * 64;

    if (t < 64) {
        const unsigned long long p = amin[row0 + t];
        const int idx = (int)(p & 0xFFFFFFFFull);
        srow[t] = idx;
        out[IDX_OFF + row0 + t] = (float)idx;
    }
    __syncthreads();

    float lsum = 0.0f;
    for (int e4 = t; e4 < 64 * 128; e4 += 256) {
        const int rl = e4 >> 7, dq = e4 & 127;
        const size_t gi = (size_t)(row0 + rl) * D + dq * 4;
        const float4 rv = *(const float4*)&residual[gi];
        const int code = srow[rl];
        const float4 ev = *(const float4*)&emb[(size_t)code * D + dq * 4];
        float4 st;
        const float dx = ev.x - rv.x, dy = ev.y - rv.y;
        const float dz = ev.z - rv.z, dw = ev.w - rv.w;
        st.x = rv.x + dx; st.y = rv.y + dy; st.z = rv.z + dz; st.w = rv.w + dw;
        *(float4*)&out[ZST_OFF + gi] = st;
        lsum += dx * dx + dy * dy + dz * dz + dw * dw;
    }
#pragma unroll
    for (int off = 32; off > 0; off >>= 1) lsum += __shfl_xor(lsum, off);
    if (lane == 0) swsum[w] = lsum;
    __syncthreads();
    if (t == 0) {
        float s = 0.0f;
#pragma unroll
        for (int ww = 0; ww < 4; ++ww) s += swsum[ww];
        atomicAdd(&wsf[WS_LOSSF], s);
    }
}

// ---------------------------------------------------------------------------
// Finalize: loss = (BETA + 1) * mean = 1.25 * sum / 16777216
// ---------------------------------------------------------------------------
__global__ void finalize_kernel(const float* __restrict__ wsf,
                                float* __restrict__ out) {
    out[LOSS_OFF] = 1.25f * wsf[WS_LOSSF] / 16777216.0f;
}

extern "C" void kernel_launch(void* const* d_in, const int* in_sizes, int n_in,
                              void* d_out, int out_size, void* d_ws, size_t ws_size,
                              hipStream_t stream) {
    const float* residual = (const float*)d_in[0];
    const float* emb      = (const float*)d_in[1];
    float* out = (float*)d_out;
    char*  wsb = (char*)d_ws;
    float* wsf = (float*)d_ws;
    unsigned long long* amin =
        (unsigned long long*)((char*)d_ws + WS_AMIN_B);

    // init packed-argmin slots to +inf (all-ones)
    hipMemsetAsync((char*)d_ws + WS_AMIN_B, 0xFF, 262144, stream);
    split_e_kernel<<<128, 256, 0, stream>>>(emb, wsb, wsf);
    split_a_kernel<<<512, 256, 0, stream>>>(residual, wsf, out);
    e2_kernel<<<256, 256, 0, stream>>>(emb, wsf);
    gemm_kernel<<<2048, 256, 0, stream>>>(wsb, wsf, amin, out);
    argzst_kernel<<<512, 256, 0, stream>>>(residual, emb, amin, wsf, out);
    finalize_kernel<<<1, 1, 0, stream>>>(wsf, out);
}